// Round 2
// baseline (51555.756 us; speedup 1.0000x reference)
//
#include <hip/hip_runtime.h>
#include <hip/hip_bf16.h>
#include <hip/hip_cooperative_groups.h>

namespace cg = cooperative_groups;

#define S_LEN 256
#define BATCH 64
#define EMB   300
#define EPAD  304
#define HID   512
#define G4H   2048
#define NCLS  25
#define TWOH  1024

using bf16 = __hip_bfloat16;

__device__ __forceinline__ float us2f(unsigned short u) {
    union { unsigned int i; float f; } v; v.i = ((unsigned int)u) << 16; return v.f;
}
__device__ __forceinline__ float sigm(float x) { return 1.f / (1.f + __expf(-x)); }

// ---------------- embedding gather: x[t][b][e] (bf16, padded to EPAD) ----------------
__global__ void embed_kernel(const int* __restrict__ ids,
                             const float* __restrict__ emb,
                             bf16* __restrict__ x)
{
    int r = blockIdx.x;            // r = t*BATCH + b
    int t = r >> 6, b = r & 63;
    int id = ids[b * S_LEN + t];
    const float* src = emb + (size_t)id * EMB;
    bf16* dst = x + (size_t)r * EPAD;
    for (int e = threadIdx.x; e < EPAD; e += blockDim.x) {
        float v = (e < EMB) ? src[e] : 0.f;
        dst[e] = __float2bfloat16(v);
    }
}

// ---------------- transpose recurrent weights: whT[wl][n][k] = W[D + k][n] ----------------
__global__ void wtrans_kernel(const float* __restrict__ w_fw0, const float* __restrict__ w_bw0,
                              const float* __restrict__ w_fw1, const float* __restrict__ w_bw1,
                              float* __restrict__ whT)
{
    __shared__ float tile[32][33];
    int wl = blockIdx.z;
    const float* W; int D;
    if (wl == 0)      { W = w_fw0; D = EMB; }
    else if (wl == 1) { W = w_bw0; D = EMB; }
    else if (wl == 2) { W = w_fw1; D = TWOH; }
    else              { W = w_bw1; D = TWOH; }
    int k0 = blockIdx.x * 32, n0 = blockIdx.y * 32;
    int tx = threadIdx.x, ty = threadIdx.y;
    tile[ty][tx] = W[(size_t)(D + k0 + ty) * G4H + n0 + tx];
    __syncthreads();
    whT[((size_t)wl * G4H + (n0 + ty)) * HID + k0 + tx] = tile[tx][ty];
}

// ---------------- input-gate precompute GEMM: G[z][t][b][4H] = gather(A) @ Wx + bias ----------------
__global__ __launch_bounds__(256)
void gates_gemm(const bf16* __restrict__ A, int strideA, int Keff,
                const float* __restrict__ W_fw, const float* __restrict__ W_bw,
                const float* __restrict__ b_fw, const float* __restrict__ b_bw,
                const int* __restrict__ lengths,
                bf16* __restrict__ G)
{
    const int z = blockIdx.z;
    const float* W    = z ? W_bw : W_fw;
    const float* bias = z ? b_bw : b_fw;
    const int m0 = blockIdx.x * 128;
    const int n0 = blockIdx.y * 128;
    const int tid = threadIdx.x;

    __shared__ __align__(16) float As[16][132];
    __shared__ __align__(16) float Bs[16][132];

    const int row_l = tid >> 1;
    const int kseg  = (tid & 1) * 8;
    int r = m0 + row_l;
    int t = r >> 6, b = r & 63;
    int st = t;
    if (z) { int len = lengths[b]; st = (t < len) ? (len - 1 - t) : t; }
    const bf16* arow = A + (size_t)(st * BATCH + b) * strideA + kseg;

    const int krow = tid >> 4;
    const int nseg = (tid & 15) * 8;
    const float* brow = W + (size_t)krow * G4H + n0 + nseg;

    const int ty = tid >> 4, tx = tid & 15;
    const int mt = ty * 8, nt = tx * 8;

    float acc[8][8];
#pragma unroll
    for (int i = 0; i < 8; ++i)
#pragma unroll
        for (int j = 0; j < 8; ++j) acc[i][j] = 0.f;

    for (int kt = 0; kt < Keff; kt += 16) {
        uint4 av = *reinterpret_cast<const uint4*>(arow + kt);
        const unsigned short* as8 = reinterpret_cast<const unsigned short*>(&av);
        float4 bld0 = *reinterpret_cast<const float4*>(brow + (size_t)kt * G4H);
        float4 bld1 = *reinterpret_cast<const float4*>(brow + (size_t)kt * G4H + 4);
#pragma unroll
        for (int j = 0; j < 8; ++j) As[kseg + j][row_l] = us2f(as8[j]);
        *reinterpret_cast<float4*>(&Bs[krow][nseg])     = bld0;
        *reinterpret_cast<float4*>(&Bs[krow][nseg + 4]) = bld1;
        __syncthreads();
#pragma unroll
        for (int k = 0; k < 16; ++k) {
            float4 a0 = *reinterpret_cast<const float4*>(&As[k][mt]);
            float4 a1 = *reinterpret_cast<const float4*>(&As[k][mt + 4]);
            float4 c0 = *reinterpret_cast<const float4*>(&Bs[k][nt]);
            float4 c1 = *reinterpret_cast<const float4*>(&Bs[k][nt + 4]);
            float a8[8] = {a0.x,a0.y,a0.z,a0.w,a1.x,a1.y,a1.z,a1.w};
            float b8[8] = {c0.x,c0.y,c0.z,c0.w,c1.x,c1.y,c1.z,c1.w};
#pragma unroll
            for (int i = 0; i < 8; ++i)
#pragma unroll
                for (int j = 0; j < 8; ++j)
                    acc[i][j] = fmaf(a8[i], b8[j], acc[i][j]);
        }
        __syncthreads();
    }

    float bv[8];
#pragma unroll
    for (int j = 0; j < 8; ++j) bv[j] = bias[n0 + nt + j];
#pragma unroll
    for (int i = 0; i < 8; ++i) {
        int rr = m0 + mt + i;
        bf16* gout = G + ((size_t)z * S_LEN * BATCH + rr) * G4H + n0 + nt;
        __align__(16) bf16 tmp[8];
#pragma unroll
        for (int j = 0; j < 8; ++j) tmp[j] = __float2bfloat16(acc[i][j] + bv[j]);
        *reinterpret_cast<uint4*>(gout) = *reinterpret_cast<const uint4*>(tmp);
    }
}

// ---------------- persistent cooperative LSTM recurrence (one layer, both dirs) ----------------
// grid = 256 blocks (2 dirs x 128 unit-chunks), block = 256 threads (thread = (b, uu)).
// Weights for this block's 4 hidden units (16 gate columns) stay in LDS for all 256 steps.
// h state broadcast through global f32 ping-pong buffers; c state lives in a register.
__global__ __launch_bounds__(256, 1)
void lstm_seq(const bf16* __restrict__ G, const float* __restrict__ whT,
              const int* __restrict__ lengths, float* __restrict__ hbuf,
              bf16* __restrict__ hcat)
{
    __shared__ __align__(16) float wlds[16][516];   // [g*4+uu][k], pad 516 spreads banks
    __shared__ __align__(16) float hl[64][68];      // h chunk [b][64k], pad 68

    const int d  = blockIdx.x >> 7;
    const int u0 = (blockIdx.x & 127) * 4;
    const int tid = threadIdx.x;
    const int b = tid >> 2, uu = tid & 3;
    const int u = u0 + uu;

    // one-time weight load: row r = g*4+u2 holds whT[d][g*512 + u0+u2][:]
    {
        int r  = tid >> 4;              // 0..15
        int g  = r >> 2, u2 = r & 3;
        int kb = (tid & 15) * 32;
        const float* src = whT + ((size_t)d * G4H + g * HID + u0 + u2) * HID + kb;
#pragma unroll
        for (int j = 0; j < 8; ++j)
            *reinterpret_cast<float4*>(&wlds[r][kb + j * 4]) =
                *reinterpret_cast<const float4*>(src + j * 4);
    }

    const int len = lengths[b];
    float c_reg = 0.f, hown = 0.f;
    cg::grid_group grid = cg::this_grid();

    for (int t = 0; t < S_LEN; ++t) {
        const float* hsrc = hbuf + (size_t)((t & 1) * 2 + d) * BATCH * HID;
        size_t gbase = ((size_t)(d * S_LEN + t) * BATCH + b) * G4H + u;
        float acc0 = __bfloat162float(G[gbase]);
        float acc1 = __bfloat162float(G[gbase + HID]);
        float acc2 = __bfloat162float(G[gbase + 2 * HID]);
        float acc3 = __bfloat162float(G[gbase + 3 * HID]);

        float4 pf[4];
#pragma unroll
        for (int i = 0; i < 4; ++i) {           // prefetch k-chunk 0
            int q = i * 256 + tid;
            int bb = q >> 4, kq = (q & 15) * 4;
            pf[i] = *reinterpret_cast<const float4*>(hsrc + (size_t)bb * HID + kq);
        }

        for (int kc = 0; kc < HID; kc += 64) {
            __syncthreads();                    // prior chunk's reads done
#pragma unroll
            for (int i = 0; i < 4; ++i) {
                int q = i * 256 + tid;
                int bb = q >> 4, kq = (q & 15) * 4;
                *reinterpret_cast<float4*>(&hl[bb][kq]) = pf[i];
            }
            __syncthreads();
            if (kc + 64 < HID) {                // async prefetch next chunk (T14)
#pragma unroll
                for (int i = 0; i < 4; ++i) {
                    int q = i * 256 + tid;
                    int bb = q >> 4, kq = (q & 15) * 4;
                    pf[i] = *reinterpret_cast<const float4*>(hsrc + (size_t)bb * HID + kc + 64 + kq);
                }
            }
#pragma unroll
            for (int kk = 0; kk < 64; kk += 8) {
                float4 ha = *reinterpret_cast<const float4*>(&hl[b][kk]);
                float4 hb = *reinterpret_cast<const float4*>(&hl[b][kk + 4]);
#pragma unroll
                for (int g = 0; g < 4; ++g) {
                    const float* wr = &wlds[g * 4 + uu][kc + kk];
                    float4 wa = *reinterpret_cast<const float4*>(wr);
                    float4 wb = *reinterpret_cast<const float4*>(wr + 4);
                    float s = ha.x*wa.x + ha.y*wa.y + ha.z*wa.z + ha.w*wa.w
                            + hb.x*wb.x + hb.y*wb.y + hb.z*wb.z + hb.w*wb.w;
                    if      (g == 0) acc0 += s;
                    else if (g == 1) acc1 += s;
                    else if (g == 2) acc2 += s;
                    else             acc3 += s;
                }
            }
        }

        bool msk = (t < len);
        float i_ = sigm(acc0);
        float j_ = tanhf(acc1);
        float f_ = sigm(acc2 + 1.0f);           // FORGET_BIAS
        float o_ = sigm(acc3);
        float cn = f_ * c_reg + i_ * j_;
        float hn = o_ * tanhf(cn);
        if (msk) c_reg = cn;
        hown = msk ? hn : hown;
        hbuf[((size_t)(((t + 1) & 1) * 2 + d) * BATCH + b) * HID + u] = hown;
        int p = (d == 1 && msk) ? (len - 1 - t) : t;
        hcat[((size_t)p * BATCH + b) * TWOH + (size_t)d * HID + u] =
            __float2bfloat16(msk ? hn : 0.f);

        __threadfence();        // release h writes (device scope)
        grid.sync();
        __threadfence();        // acquire: invalidate L1 before next step's reads
    }
}

// ---------------- dense + softmax: out[b][s][c] ----------------
__global__ __launch_bounds__(256)
void dense_softmax(const bf16* __restrict__ h, const float* __restrict__ wd,
                   const float* __restrict__ bd, float* __restrict__ out)
{
    __shared__ __align__(16) bf16 wdT[NCLS][1032];
    for (int i = threadIdx.x; i < TWOH * NCLS; i += 256) {
        int k = i / NCLS, c = i % NCLS;    // wd[k][c]
        wdT[c][k] = __float2bfloat16(wd[i]);
    }
    __syncthreads();
    const int c  = threadIdx.x & 31;
    const int rl = threadIdx.x >> 5;
#pragma unroll 1
    for (int pass = 0; pass < 8; ++pass) {
        int r = blockIdx.x * 64 + pass * 8 + rl;   // r = s*BATCH + b
        const bf16* hrow = h + (size_t)r * TWOH;
        float acc = -1e30f;
        if (c < NCLS) {
            acc = 0.f;
            for (int k = 0; k < TWOH; k += 8) {
                uint4 hv = *reinterpret_cast<const uint4*>(hrow + k);
                uint4 wv = *reinterpret_cast<const uint4*>(&wdT[c][k]);
                const unsigned short* hs  = reinterpret_cast<const unsigned short*>(&hv);
                const unsigned short* wsp = reinterpret_cast<const unsigned short*>(&wv);
#pragma unroll
                for (int j = 0; j < 8; ++j) acc += us2f(hs[j]) * us2f(wsp[j]);
            }
            acc += bd[c];
        }
        float mx = acc;
#pragma unroll
        for (int o = 16; o; o >>= 1) mx = fmaxf(mx, __shfl_xor(mx, o, 32));
        float e = (c < NCLS) ? __expf(acc - mx) : 0.f;
        float sm = e;
#pragma unroll
        for (int o = 16; o; o >>= 1) sm += __shfl_xor(sm, o, 32);
        if (c < NCLS) {
            int s = r >> 6, b = r & 63;
            out[((size_t)b * S_LEN + s) * NCLS + c] = e / sm;
        }
    }
}

extern "C" void kernel_launch(void* const* d_in, const int* in_sizes, int n_in,
                              void* d_out, int out_size, void* d_ws, size_t ws_size,
                              hipStream_t stream)
{
    const int*   ids   = (const int*)  d_in[0];
    const int*   lens  = (const int*)  d_in[1];
    const float* emb   = (const float*)d_in[2];
    const float* w_fw0 = (const float*)d_in[3];
    const float* b_fw0 = (const float*)d_in[4];
    const float* w_bw0 = (const float*)d_in[5];
    const float* b_bw0 = (const float*)d_in[6];
    const float* w_fw1 = (const float*)d_in[7];
    const float* b_fw1 = (const float*)d_in[8];
    const float* w_bw1 = (const float*)d_in[9];
    const float* b_bw1 = (const float*)d_in[10];
    const float* wd    = (const float*)d_in[11];
    const float* bd    = (const float*)d_in[12];
    float* out = (float*)d_out;

    char* ws = (char*)d_ws;
    size_t off = 0;
    auto alloc = [&](size_t bytes) {
        void* p = ws + off;
        off += (bytes + 255) & ~(size_t)255;
        return p;
    };
    bf16*  x      = (bf16*) alloc((size_t)S_LEN * BATCH * EPAD * 2);
    bf16*  G      = (bf16*) alloc((size_t)2 * S_LEN * BATCH * G4H * 2);
    bf16*  hcat0  = (bf16*) alloc((size_t)S_LEN * BATCH * TWOH * 2);
    bf16*  hcat1  = (bf16*) alloc((size_t)S_LEN * BATCH * TWOH * 2);
    float* whT    = (float*)alloc((size_t)4 * G4H * HID * 4);
    float* hbuf   = (float*)alloc((size_t)2 * 2 * BATCH * HID * 4);

    embed_kernel<<<S_LEN * BATCH, 128, 0, stream>>>(ids, emb, x);
    wtrans_kernel<<<dim3(16, 64, 4), dim3(32, 32), 0, stream>>>(w_fw0, w_bw0, w_fw1, w_bw1, whT);

    for (int layer = 0; layer < 2; ++layer) {
        hipMemsetAsync(hbuf, 0, (size_t)2 * 2 * BATCH * HID * 4, stream);
        const bf16* Ain   = layer ? hcat0 : x;
        int strideA       = layer ? TWOH : EPAD;
        const float* Wf   = layer ? w_fw1 : w_fw0;
        const float* Wb   = layer ? w_bw1 : w_bw0;
        const float* bfp  = layer ? b_fw1 : b_fw0;
        const float* bbp  = layer ? b_bw1 : b_bw0;
        bf16* hcat        = layer ? hcat1 : hcat0;
        const float* whTL = whT + (size_t)layer * 2 * G4H * HID;

        gates_gemm<<<dim3(128, 16, 2), 256, 0, stream>>>(Ain, strideA, strideA,
                                                         Wf, Wb, bfp, bbp, lens, G);

        const bf16*  Gp   = G;
        const float* whTp = whTL;
        const int*   lnp  = lens;
        float*       hbp  = hbuf;
        bf16*        hcp  = hcat;
        void* args[5] = { &Gp, &whTp, &lnp, &hbp, &hcp };
        hipLaunchCooperativeKernel(lstm_seq, dim3(256), dim3(256), args, 0, stream);
    }
    dense_softmax<<<256, 256, 0, stream>>>(hcat1, wd, bd, out);

    (void)in_sizes; (void)n_in; (void)out_size; (void)ws_size;
}

// Round 3
// 13705.493 us; speedup vs baseline: 3.7617x; 3.7617x over previous
//
#include <hip/hip_runtime.h>
#include <hip/hip_bf16.h>

#define S_LEN 256
#define BATCH 64
#define EMB   300
#define EPAD  304
#define HID   512
#define G4H   2048
#define NCLS  25
#define TWOH  1024

using bf16 = __hip_bfloat16;

__device__ __forceinline__ float us2f(unsigned short u) {
    union { unsigned int i; float f; } v; v.i = ((unsigned int)u) << 16; return v.f;
}
__device__ __forceinline__ float sigm(float x) { return 1.f / (1.f + __expf(-x)); }

// ---------------- embedding gather: x[t][b][e] (bf16, padded to EPAD) ----------------
__global__ void embed_kernel(const int* __restrict__ ids,
                             const float* __restrict__ emb,
                             bf16* __restrict__ x)
{
    int r = blockIdx.x;            // r = t*BATCH + b
    int t = r >> 6, b = r & 63;
    int id = ids[b * S_LEN + t];
    const float* src = emb + (size_t)id * EMB;
    bf16* dst = x + (size_t)r * EPAD;
    for (int e = threadIdx.x; e < EPAD; e += blockDim.x) {
        float v = (e < EMB) ? src[e] : 0.f;
        dst[e] = __float2bfloat16(v);
    }
}

// ---------------- transpose recurrent weights: whT[wl][n][k] = W[D + k][n] ----------------
__global__ void wtrans_kernel(const float* __restrict__ w_fw0, const float* __restrict__ w_bw0,
                              const float* __restrict__ w_fw1, const float* __restrict__ w_bw1,
                              float* __restrict__ whT)
{
    __shared__ float tile[32][33];
    int wl = blockIdx.z;
    const float* W; int D;
    if (wl == 0)      { W = w_fw0; D = EMB; }
    else if (wl == 1) { W = w_bw0; D = EMB; }
    else if (wl == 2) { W = w_fw1; D = TWOH; }
    else              { W = w_bw1; D = TWOH; }
    int k0 = blockIdx.x * 32, n0 = blockIdx.y * 32;
    int tx = threadIdx.x, ty = threadIdx.y;
    tile[ty][tx] = W[(size_t)(D + k0 + ty) * G4H + n0 + tx];
    __syncthreads();
    whT[((size_t)wl * G4H + (n0 + ty)) * HID + k0 + tx] = tile[tx][ty];
}

// ---------------- input-gate precompute GEMM: G[z][t][b][4H] = gather(A) @ Wx + bias ----------------
__global__ __launch_bounds__(256)
void gates_gemm(const bf16* __restrict__ A, int strideA, int Keff,
                const float* __restrict__ W_fw, const float* __restrict__ W_bw,
                const float* __restrict__ b_fw, const float* __restrict__ b_bw,
                const int* __restrict__ lengths,
                bf16* __restrict__ G)
{
    const int z = blockIdx.z;
    const float* W    = z ? W_bw : W_fw;
    const float* bias = z ? b_bw : b_fw;
    const int m0 = blockIdx.x * 128;
    const int n0 = blockIdx.y * 128;
    const int tid = threadIdx.x;

    __shared__ __align__(16) float As[16][132];
    __shared__ __align__(16) float Bs[16][132];

    const int row_l = tid >> 1;
    const int kseg  = (tid & 1) * 8;
    int r = m0 + row_l;
    int t = r >> 6, b = r & 63;
    int st = t;
    if (z) { int len = lengths[b]; st = (t < len) ? (len - 1 - t) : t; }
    const bf16* arow = A + (size_t)(st * BATCH + b) * strideA + kseg;

    const int krow = tid >> 4;
    const int nseg = (tid & 15) * 8;
    const float* brow = W + (size_t)krow * G4H + n0 + nseg;

    const int ty = tid >> 4, tx = tid & 15;
    const int mt = ty * 8, nt = tx * 8;

    float acc[8][8];
#pragma unroll
    for (int i = 0; i < 8; ++i)
#pragma unroll
        for (int j = 0; j < 8; ++j) acc[i][j] = 0.f;

    for (int kt = 0; kt < Keff; kt += 16) {
        uint4 av = *reinterpret_cast<const uint4*>(arow + kt);
        const unsigned short* as8 = reinterpret_cast<const unsigned short*>(&av);
        float4 bld0 = *reinterpret_cast<const float4*>(brow + (size_t)kt * G4H);
        float4 bld1 = *reinterpret_cast<const float4*>(brow + (size_t)kt * G4H + 4);
#pragma unroll
        for (int j = 0; j < 8; ++j) As[kseg + j][row_l] = us2f(as8[j]);
        *reinterpret_cast<float4*>(&Bs[krow][nseg])     = bld0;
        *reinterpret_cast<float4*>(&Bs[krow][nseg + 4]) = bld1;
        __syncthreads();
#pragma unroll
        for (int k = 0; k < 16; ++k) {
            float4 a0 = *reinterpret_cast<const float4*>(&As[k][mt]);
            float4 a1 = *reinterpret_cast<const float4*>(&As[k][mt + 4]);
            float4 c0 = *reinterpret_cast<const float4*>(&Bs[k][nt]);
            float4 c1 = *reinterpret_cast<const float4*>(&Bs[k][nt + 4]);
            float a8[8] = {a0.x,a0.y,a0.z,a0.w,a1.x,a1.y,a1.z,a1.w};
            float b8[8] = {c0.x,c0.y,c0.z,c0.w,c1.x,c1.y,c1.z,c1.w};
#pragma unroll
            for (int i = 0; i < 8; ++i)
#pragma unroll
                for (int j = 0; j < 8; ++j)
                    acc[i][j] = fmaf(a8[i], b8[j], acc[i][j]);
        }
        __syncthreads();
    }

    float bv[8];
#pragma unroll
    for (int j = 0; j < 8; ++j) bv[j] = bias[n0 + nt + j];
#pragma unroll
    for (int i = 0; i < 8; ++i) {
        int rr = m0 + mt + i;
        bf16* gout = G + ((size_t)z * S_LEN * BATCH + rr) * G4H + n0 + nt;
        __align__(16) bf16 tmp[8];
#pragma unroll
        for (int j = 0; j < 8; ++j) tmp[j] = __float2bfloat16(acc[i][j] + bv[j]);
        *reinterpret_cast<uint4*>(gout) = *reinterpret_cast<const uint4*>(tmp);
    }
}

// ---------------- persistent LSTM recurrence (one layer, both dirs) ----------------
// grid = 256 blocks (2 dirs x 128 unit-chunks), block = 256 threads (thread = (b, uu)).
// Block's 16 gate columns (4 units x 4 gates) of Wh stay in LDS for all 256 steps.
// Cross-block h exchange + per-step barrier use RELAXED AGENT-scope atomics only
// (sc0/sc1 write-through + read-through) — NO fences, so no per-step L2
// writeback/invalidate (that was round 1's 97 us/step).
__global__ __launch_bounds__(256, 1)
void lstm_seq(const bf16* __restrict__ G, const float* __restrict__ whT,
              const int* __restrict__ lengths, float* __restrict__ hbuf,
              unsigned int* __restrict__ flags, bf16* __restrict__ hcat)
{
    __shared__ __align__(16) float wlds[16][516];   // [g*4+uu][k]
    __shared__ __align__(16) float hl[64][68];      // h chunk [b][64k]

    const int d   = blockIdx.x >> 7;
    const int u0  = (blockIdx.x & 127) * 4;
    const int tid = threadIdx.x;
    const int b = tid >> 2, uu = tid & 3;
    const int u = u0 + uu;

    // one-time weight load: row r = g*4+u2 holds whT[d][g*512 + u0+u2][:]
    {
        int r  = tid >> 4;              // 0..15
        int g  = r >> 2, u2 = r & 3;
        int kb = (tid & 15) * 32;
        const float* src = whT + ((size_t)d * G4H + g * HID + u0 + u2) * HID + kb;
#pragma unroll
        for (int j = 0; j < 8; ++j)
            *reinterpret_cast<float4*>(&wlds[r][kb + j * 4]) =
                *reinterpret_cast<const float4*>(src + j * 4);
    }

    const int len = lengths[b];
    float c_reg = 0.f, hown = 0.f;

    // staging-thread geometry: element e = i*256+tid of a 64x64 chunk
    int sbb[16], skq[16];
#pragma unroll
    for (int i = 0; i < 16; ++i) {
        int e = i * 256 + tid;
        sbb[i] = e >> 6; skq[i] = e & 63;
    }

    for (int t = 0; t < S_LEN; ++t) {
        const float* hsrc = hbuf + (size_t)((t & 1) * 2 + d) * BATCH * HID;
        size_t gbase = ((size_t)(d * S_LEN + t) * BATCH + b) * G4H + u;
        float acc0 = __bfloat162float(G[gbase]);
        float acc1 = __bfloat162float(G[gbase + HID]);
        float acc2 = __bfloat162float(G[gbase + 2 * HID]);
        float acc3 = __bfloat162float(G[gbase + 3 * HID]);

        float pf[16];
#pragma unroll
        for (int i = 0; i < 16; ++i)     // prefetch chunk 0 (agent-coherent reads)
            pf[i] = __hip_atomic_load(hsrc + (size_t)sbb[i] * HID + skq[i],
                                      __ATOMIC_RELAXED, __HIP_MEMORY_SCOPE_AGENT);

        for (int kc = 0; kc < HID; kc += 64) {
            __syncthreads();                    // prior chunk reads done + pf drained
#pragma unroll
            for (int i = 0; i < 16; ++i) hl[sbb[i]][skq[i]] = pf[i];
            __syncthreads();
            if (kc + 64 < HID) {
#pragma unroll
                for (int i = 0; i < 16; ++i)
                    pf[i] = __hip_atomic_load(hsrc + (size_t)sbb[i] * HID + kc + 64 + skq[i],
                                              __ATOMIC_RELAXED, __HIP_MEMORY_SCOPE_AGENT);
            }
#pragma unroll
            for (int kk = 0; kk < 64; kk += 8) {
                float4 ha = *reinterpret_cast<const float4*>(&hl[b][kk]);
                float4 hb = *reinterpret_cast<const float4*>(&hl[b][kk + 4]);
#pragma unroll
                for (int g = 0; g < 4; ++g) {
                    const float* wr = &wlds[g * 4 + uu][kc + kk];
                    float4 wa = *reinterpret_cast<const float4*>(wr);
                    float4 wb = *reinterpret_cast<const float4*>(wr + 4);
                    float s = ha.x*wa.x + ha.y*wa.y + ha.z*wa.z + ha.w*wa.w
                            + hb.x*wb.x + hb.y*wb.y + hb.z*wb.z + hb.w*wb.w;
                    if      (g == 0) acc0 += s;
                    else if (g == 1) acc1 += s;
                    else if (g == 2) acc2 += s;
                    else             acc3 += s;
                }
            }
        }

        bool msk = (t < len);
        float i_ = sigm(acc0);
        float j_ = tanhf(acc1);
        float f_ = sigm(acc2 + 1.0f);           // FORGET_BIAS
        float o_ = sigm(acc3);
        float cn = f_ * c_reg + i_ * j_;
        float hn = o_ * tanhf(cn);
        if (msk) c_reg = cn;
        hown = msk ? hn : hown;

        // publish h_t (write-through, agent-coherent)
        __hip_atomic_store(&hbuf[((size_t)(((t + 1) & 1) * 2 + d) * BATCH + b) * HID + u],
                           hown, __ATOMIC_RELAXED, __HIP_MEMORY_SCOPE_AGENT);
        int p = (d == 1 && msk) ? (len - 1 - t) : t;
        hcat[((size_t)p * BATCH + b) * TWOH + (size_t)d * HID + u] =
            __float2bfloat16(msk ? hn : 0.f);

        // ---- fence-free grid barrier ----
        asm volatile("s_waitcnt vmcnt(0)" ::: "memory");  // h stores at coherence point
        __syncthreads();                                   // all waves drained
        if (tid == 0)
            __hip_atomic_store(&flags[(size_t)t * 256 + blockIdx.x], 1u,
                               __ATOMIC_RELAXED, __HIP_MEMORY_SCOPE_AGENT);
        if (tid < 64) {
            const unsigned int* fb = flags + (size_t)t * 256;
            while (true) {
                unsigned f0 = __hip_atomic_load(fb + tid,       __ATOMIC_RELAXED, __HIP_MEMORY_SCOPE_AGENT);
                unsigned f1 = __hip_atomic_load(fb + tid + 64,  __ATOMIC_RELAXED, __HIP_MEMORY_SCOPE_AGENT);
                unsigned f2 = __hip_atomic_load(fb + tid + 128, __ATOMIC_RELAXED, __HIP_MEMORY_SCOPE_AGENT);
                unsigned f3 = __hip_atomic_load(fb + tid + 192, __ATOMIC_RELAXED, __HIP_MEMORY_SCOPE_AGENT);
                if (__all((f0 & f1 & f2 & f3) == 1u)) break;
                __builtin_amdgcn_s_sleep(2);
            }
        }
        __syncthreads();
        asm volatile("" ::: "memory");
    }
}

// ---------------- dense + softmax: out[b][s][c] ----------------
__global__ __launch_bounds__(256)
void dense_softmax(const bf16* __restrict__ h, const float* __restrict__ wd,
                   const float* __restrict__ bd, float* __restrict__ out)
{
    __shared__ __align__(16) bf16 wdT[NCLS][1032];
    for (int i = threadIdx.x; i < TWOH * NCLS; i += 256) {
        int k = i / NCLS, c = i % NCLS;    // wd[k][c]
        wdT[c][k] = __float2bfloat16(wd[i]);
    }
    __syncthreads();
    const int c  = threadIdx.x & 31;
    const int rl = threadIdx.x >> 5;
#pragma unroll 1
    for (int pass = 0; pass < 8; ++pass) {
        int r = blockIdx.x * 64 + pass * 8 + rl;   // r = s*BATCH + b
        const bf16* hrow = h + (size_t)r * TWOH;
        float acc = -1e30f;
        if (c < NCLS) {
            acc = 0.f;
            for (int k = 0; k < TWOH; k += 8) {
                uint4 hv = *reinterpret_cast<const uint4*>(hrow + k);
                uint4 wv = *reinterpret_cast<const uint4*>(&wdT[c][k]);
                const unsigned short* hs  = reinterpret_cast<const unsigned short*>(&hv);
                const unsigned short* wsp = reinterpret_cast<const unsigned short*>(&wv);
#pragma unroll
                for (int j = 0; j < 8; ++j) acc += us2f(hs[j]) * us2f(wsp[j]);
            }
            acc += bd[c];
        }
        float mx = acc;
#pragma unroll
        for (int o = 16; o; o >>= 1) mx = fmaxf(mx, __shfl_xor(mx, o, 32));
        float e = (c < NCLS) ? __expf(acc - mx) : 0.f;
        float sm = e;
#pragma unroll
        for (int o = 16; o; o >>= 1) sm += __shfl_xor(sm, o, 32);
        if (c < NCLS) {
            int s = r >> 6, b = r & 63;
            out[((size_t)b * S_LEN + s) * NCLS + c] = e / sm;
        }
    }
}

extern "C" void kernel_launch(void* const* d_in, const int* in_sizes, int n_in,
                              void* d_out, int out_size, void* d_ws, size_t ws_size,
                              hipStream_t stream)
{
    const int*   ids   = (const int*)  d_in[0];
    const int*   lens  = (const int*)  d_in[1];
    const float* emb   = (const float*)d_in[2];
    const float* w_fw0 = (const float*)d_in[3];
    const float* b_fw0 = (const float*)d_in[4];
    const float* w_bw0 = (const float*)d_in[5];
    const float* b_bw0 = (const float*)d_in[6];
    const float* w_fw1 = (const float*)d_in[7];
    const float* b_fw1 = (const float*)d_in[8];
    const float* w_bw1 = (const float*)d_in[9];
    const float* b_bw1 = (const float*)d_in[10];
    const float* wd    = (const float*)d_in[11];
    const float* bd    = (const float*)d_in[12];
    float* out = (float*)d_out;

    char* ws = (char*)d_ws;
    size_t off = 0;
    auto alloc = [&](size_t bytes) {
        void* p = ws + off;
        off += (bytes + 255) & ~(size_t)255;
        return p;
    };
    bf16*  x      = (bf16*) alloc((size_t)S_LEN * BATCH * EPAD * 2);
    bf16*  G      = (bf16*) alloc((size_t)2 * S_LEN * BATCH * G4H * 2);
    bf16*  hcat0  = (bf16*) alloc((size_t)S_LEN * BATCH * TWOH * 2);
    bf16*  hcat1  = (bf16*) alloc((size_t)S_LEN * BATCH * TWOH * 2);
    float* whT    = (float*)alloc((size_t)4 * G4H * HID * 4);
    float* hbuf   = (float*)alloc((size_t)2 * 2 * BATCH * HID * 4);
    unsigned int* flags = (unsigned int*)alloc((size_t)S_LEN * 256 * 4);

    embed_kernel<<<S_LEN * BATCH, 128, 0, stream>>>(ids, emb, x);
    wtrans_kernel<<<dim3(16, 64, 4), dim3(32, 32), 0, stream>>>(w_fw0, w_bw0, w_fw1, w_bw1, whT);

    for (int layer = 0; layer < 2; ++layer) {
        hipMemsetAsync(hbuf, 0, (size_t)2 * 2 * BATCH * HID * 4, stream);
        hipMemsetAsync(flags, 0, (size_t)S_LEN * 256 * 4, stream);
        const bf16* Ain   = layer ? hcat0 : x;
        int strideA       = layer ? TWOH : EPAD;
        const float* Wf   = layer ? w_fw1 : w_fw0;
        const float* Wb   = layer ? w_bw1 : w_bw0;
        const float* bfp  = layer ? b_fw1 : b_fw0;
        const float* bbp  = layer ? b_bw1 : b_bw0;
        bf16* hcat        = layer ? hcat1 : hcat0;
        const float* whTL = whT + (size_t)layer * 2 * G4H * HID;

        gates_gemm<<<dim3(128, 16, 2), 256, 0, stream>>>(Ain, strideA, strideA,
                                                         Wf, Wb, bfp, bbp, lens, G);

        const bf16*  Gp   = G;
        const float* whTp = whTL;
        const int*   lnp  = lens;
        float*       hbp  = hbuf;
        unsigned int* flp = flags;
        bf16*        hcp  = hcat;
        void* args[6] = { &Gp, &whTp, &lnp, &hbp, &flp, &hcp };
        hipLaunchCooperativeKernel(lstm_seq, dim3(256), dim3(256), args, 0, stream);
    }
    dense_softmax<<<256, 256, 0, stream>>>(hcat1, wd, bd, out);

    (void)in_sizes; (void)n_in; (void)out_size; (void)ws_size;
}